// Round 1
// 383.357 us; speedup vs baseline: 1.0137x; 1.0137x over previous
//
#include <hip/hip_runtime.h>

#define B_  4
#define N_  131072
#define J_  55
#define JP_ 56        // padded J (pad entries are zero)
#define D_  64
#define D3_ 262144    // 64^3
#define PF_ 486
#define COLS_ 31425   // M*3

#define BL16(u) __uint_as_float((u) << 16)
#define BH16(u) __uint_as_float((u) & 0xffff0000u)

// native 4-float vector for nontemporal builtins (HIP float4 is a class)
typedef float vfloat4 __attribute__((ext_vector_type(4)));

__device__ __forceinline__ unsigned short f2bf(float v) {
    unsigned u = __float_as_uint(v);
    u += 0x7fffu + ((u >> 16) & 1u);   // round-to-nearest-even
    return (unsigned short)(u >> 16);
}

// ------- off_full: pose part (pf @ podir, p-chunked) + shape part at pc==0 -
__global__ void k_off_pose(const float* __restrict__ pf,
                           const float* __restrict__ podir,
                           const float* __restrict__ betas,
                           const float* __restrict__ spdir,
                           float* __restrict__ off_full) {
    int col = blockIdx.x * 256 + threadIdx.x;
    if (col >= COLS_) return;
    int pc = blockIdx.y;
    float a0 = 0.f, a1 = 0.f, a2 = 0.f, a3 = 0.f;
    if (pc == 0) {   // shape blend term rides along in chunk 0
        float sp[10];
#pragma unroll
        for (int l = 0; l < 10; ++l) sp[l] = spdir[col * 10 + l];
#pragma unroll
        for (int l = 0; l < 10; ++l) {
            a0 += betas[0 * 10 + l] * sp[l];
            a1 += betas[1 * 10 + l] * sp[l];
            a2 += betas[2 * 10 + l] * sp[l];
            a3 += betas[3 * 10 + l] * sp[l];
        }
    }
    int p0 = pc * 61;
    int p1 = p0 + 61; if (p1 > PF_) p1 = PF_;
    for (int p = p0; p < p1; ++p) {
        float v = podir[(size_t)p * COLS_ + col];
        a0 += pf[0 * PF_ + p] * v;
        a1 += pf[1 * PF_ + p] * v;
        a2 += pf[2 * PF_ + p] * v;
        a3 += pf[3 * PF_ + p] * v;
    }
    atomicAdd(&off_full[0 * COLS_ + col], a0);
    atomicAdd(&off_full[1 * COLS_ + col], a1);
    atomicAdd(&off_full[2 * COLS_ + col], a2);
    atomicAdd(&off_full[3 * COLS_ + col], a3);
}

// ---------------- tfs = A @ A_inv, padded to JP_ joints --------------------
__global__ void k_tfs(const float* __restrict__ A,
                      const float* __restrict__ Ainv,
                      float* __restrict__ tfsP) {
    int tid = blockIdx.x * 256 + threadIdx.x;
    if (tid >= B_ * JP_ * 16) return;
    int rc = tid & 15;
    int jb = tid >> 4;
    int j = jb % JP_;
    int b = jb / JP_;
    float v = 0.f;
    if (j < J_) {
        int r = rc >> 2, c = rc & 3;
#pragma unroll
        for (int k = 0; k < 4; ++k)
            v += A[((b * J_ + j) * 4 + r) * 4 + k] * Ainv[(j * 4 + k) * 4 + c];
    }
    tfsP[tid] = v;
}

// --- k_G: per-grid-vertex blended transform  G[b][v][16] (bf16), S[v] (f32)
// G[v] = sum_j vox[j][v] * tfs[b][j];  S[v] = sum_j vox[j][v]  (b-independent)
// Exploits linearity of trilerp: T(p) = sum_corners wc * G[corner].
__global__ __launch_bounds__(256) void k_G(
    const float* __restrict__ vox, const float* __restrict__ tfsP,
    uint4* __restrict__ Gtb, float* __restrict__ Stb) {
    int v = blockIdx.x * 256 + threadIdx.x;
    float g[4][16];
    float s = 0.f;
#pragma unroll
    for (int b = 0; b < 4; ++b)
#pragma unroll
        for (int r = 0; r < 16; ++r) g[b][r] = 0.f;
    for (int j = 0; j < J_; ++j) {
        float w = vox[(size_t)j * D3_ + v];   // coalesced stream, read once
        s += w;
#pragma unroll
        for (int b = 0; b < 4; ++b) {
            const float* tr = tfsP + (b * JP_ + j) * 16;  // uniform -> s_load
#pragma unroll
            for (int r = 0; r < 16; ++r) g[b][r] += w * tr[r];
        }
    }
    Stb[v] = s;
#pragma unroll
    for (int b = 0; b < 4; ++b) {
        unsigned gw[8];
#pragma unroll
        for (int k = 0; k < 8; ++k)
            gw[k] = (unsigned)f2bf(g[b][2 * k]) |
                    ((unsigned)f2bf(g[b][2 * k + 1]) << 16);
        uint4* gp = Gtb + ((size_t)b * D3_ + v) * 2;
        gp[0] = make_uint4(gw[0], gw[1], gw[2], gw[3]);
        gp[1] = make_uint4(gw[4], gw[5], gw[6], gw[7]);
    }
}

// accumulate 8 T-entries from two adjacent-corner G rows (bf16-packed)
#define ACC8(Toff, qa, qb)                                 \
    T[Toff + 0] += w0 * BL16(qa.x) + w1 * BL16(qb.x);      \
    T[Toff + 1] += w0 * BH16(qa.x) + w1 * BH16(qb.x);      \
    T[Toff + 2] += w0 * BL16(qa.y) + w1 * BL16(qb.y);      \
    T[Toff + 3] += w0 * BH16(qa.y) + w1 * BH16(qb.y);      \
    T[Toff + 4] += w0 * BL16(qa.z) + w1 * BL16(qb.z);      \
    T[Toff + 5] += w0 * BH16(qa.z) + w1 * BH16(qb.z);      \
    T[Toff + 6] += w0 * BL16(qa.w) + w1 * BL16(qb.w);      \
    T[Toff + 7] += w0 * BH16(qa.w) + w1 * BH16(qb.w);

// ---------------- single fused main pass (n-order, coalesced) --------------
__global__ __launch_bounds__(256) void k_main(
    const float* __restrict__ pts, const int* __restrict__ faces,
    const float* __restrict__ poseoff, const int* __restrict__ mask,
    const float* __restrict__ vox_scale, const float* __restrict__ vox_offset,
    const float* __restrict__ off_full, const float* __restrict__ tfsP,
    const float* __restrict__ lbsw, const uint4* __restrict__ Gtb,
    const float* __restrict__ Stb,
    float* __restrict__ out_posed, float* __restrict__ out_T) {
    int b = blockIdx.y;
    int n = blockIdx.x * 256 + threadIdx.x;
    int i = (b << 17) | n;

    float px = pts[3 * i + 0], py = pts[3 * i + 1], pz = pts[3 * i + 2];
    int f0 = faces[3 * n + 0], f1 = faces[3 * n + 1], f2 = faces[3 * n + 2];
    const float* ob = off_full + b * COLS_;
    const float c3 = 1.f / 3.f;
    float ox = (ob[f0 * 3 + 0] + ob[f1 * 3 + 0] + ob[f2 * 3 + 0]) * c3;
    float oy = (ob[f0 * 3 + 1] + ob[f1 * 3 + 1] + ob[f2 * 3 + 1]) * c3;
    float oz = (ob[f0 * 3 + 2] + ob[f1 * 3 + 2] + ob[f2 * 3 + 2]) * c3;
    float x0 = px + ox - poseoff[3 * n + 0];
    float x1 = py + oy - poseoff[3 * n + 1];
    float x2 = pz + oz - poseoff[3 * n + 2];

    float T[16];
#pragma unroll
    for (int r = 0; r < 16; ++r) T[r] = 0.f;
    float wsum = 0.f;

    if (mask[i] > 0) {
        // explicit skinning weights path
        const float* lw = lbsw + (size_t)n * J_;
        const float* tb = tfsP + b * (JP_ * 16);   // uniform -> s_load
        for (int j = 0; j < J_; ++j) {
            float w = lw[j];
            wsum += w;
            const float* tr = tb + j * 16;
#pragma unroll
            for (int r = 0; r < 16; ++r) T[r] += w * tr[r];
        }
    } else {
        // voxel path: 8-corner blend of precomputed per-vertex transforms
        float sx = vox_scale[0], sy = vox_scale[1], sz = vox_scale[2];
        float o0 = vox_offset[0], o1 = vox_offset[1], o2 = vox_offset[2];
        float gx = fminf(fmaxf(px * sx + o0, -1.f), 1.f);
        float gy = fminf(fmaxf(py * sy + o1, -1.f), 1.f);
        float gz = fminf(fmaxf(pz * sz + o2, -1.f), 1.f);
        float tx = (gx + 1.f) * 0.5f * (D_ - 1);
        float ty = (gy + 1.f) * 0.5f * (D_ - 1);
        float tz = (gz + 1.f) * 0.5f * (D_ - 1);
        int ix = (int)floorf(tx); if (ix > D_ - 2) ix = D_ - 2; if (ix < 0) ix = 0;
        int iy = (int)floorf(ty); if (iy > D_ - 2) iy = D_ - 2; if (iy < 0) iy = 0;
        int iz = (int)floorf(tz); if (iz > D_ - 2) iz = D_ - 2; if (iz < 0) iz = 0;
        float fx = tx - ix, fy = ty - iy, fz = tz - iz;
        int cell = (ix * D_ + iy) * D_ + iz;
        const uint4* Gb = Gtb + (size_t)b * D3_ * 2;
#pragma unroll
        for (int cc = 0; cc < 4; ++cc) {
            int fid = cell + ((cc & 2) ? D_ * D_ : 0) + ((cc & 1) ? D_ : 0);
            float wxy = ((cc & 2) ? fx : 1.f - fx) * ((cc & 1) ? fy : 1.f - fy);
            float w0 = wxy * (1.f - fz);
            float w1 = wxy * fz;
            const uint4* R = Gb + (size_t)fid * 2;   // 64B: rows fid, fid+1
            uint4 q0 = R[0], q1 = R[1], q2 = R[2], q3 = R[3];
            wsum += w0 * Stb[fid] + w1 * Stb[fid + 1];
            ACC8(0, q0, q2)
            ACC8(8, q1, q3)
        }
    }

    float inv = 1.f / fmaxf(wsum, 1e-8f);
    float t[16];
#pragma unroll
    for (int r = 0; r < 16; ++r) t[r] = T[r] * inv;
    out_posed[3 * i + 0] = t[0] * x0 + t[1] * x1 + t[2] * x2 + t[3];
    out_posed[3 * i + 1] = t[4] * x0 + t[5] * x1 + t[6] * x2 + t[7];
    out_posed[3 * i + 2] = t[8] * x0 + t[9] * x1 + t[10] * x2 + t[11];
    vfloat4* to = (vfloat4*)(out_T + (size_t)i * 16);
    vfloat4 r0 = { t[0], t[1], t[2], t[3] };
    vfloat4 r1 = { t[4], t[5], t[6], t[7] };
    vfloat4 r2 = { t[8], t[9], t[10], t[11] };
    vfloat4 r3 = { t[12], t[13], t[14], t[15] };
    __builtin_nontemporal_store(r0, to + 0);
    __builtin_nontemporal_store(r1, to + 1);
    __builtin_nontemporal_store(r2, to + 2);
    __builtin_nontemporal_store(r3, to + 3);
}

extern "C" void kernel_launch(void* const* d_in, const int* in_sizes, int n_in,
                              void* d_out, int out_size, void* d_ws, size_t ws_size,
                              hipStream_t stream) {
    const float* pts      = (const float*)d_in[0];
    const float* betas    = (const float*)d_in[1];
    const float* pf       = (const float*)d_in[2];
    const float* spdir    = (const float*)d_in[3];
    const float* podir    = (const float*)d_in[4];
    const int*   faces    = (const int*)d_in[5];
    const float* tfs_A    = (const float*)d_in[6];
    const float* tfs_inv  = (const float*)d_in[7];
    const float* poseoff  = (const float*)d_in[8];
    const float* lbsw     = (const float*)d_in[9];
    const float* vox      = (const float*)d_in[10];
    const float* vscale   = (const float*)d_in[11];
    const float* voffset  = (const float*)d_in[12];
    const int*   mask     = (const int*)d_in[13];

    // workspace layout (256B-aligned)
    char* w = (char*)d_ws;
    uint4* Gtb      = (uint4*)w;                       // 33,554,432 B
    float* Stb      = (float*)(w + 33554432);          //  1,048,576 B
    float* off_full = (float*)(w + 34603008);          //    503,040 B
    float* tfsP     = (float*)(w + 35106048);          //     14,336 B
    // total: 35,120,384 B

    float* out_posed = (float*)d_out;
    float* out_T     = out_posed + (size_t)B_ * N_ * 3;

    (void)hipMemsetAsync(off_full, 0, 503040, stream);
    k_tfs<<<(B_ * JP_ * 16 + 255) / 256, 256, 0, stream>>>(tfs_A, tfs_inv, tfsP);
    k_G<<<D3_ / 256, 256, 0, stream>>>(vox, tfsP, Gtb, Stb);
    dim3 gpose((COLS_ + 255) / 256, 8);
    k_off_pose<<<gpose, 256, 0, stream>>>(pf, podir, betas, spdir, off_full);

    dim3 g2(N_ / 256, B_);
    k_main<<<g2, 256, 0, stream>>>(pts, faces, poseoff, mask, vscale, voffset,
                                   off_full, tfsP, lbsw, Gtb, Stb,
                                   out_posed, out_T);
}

// Round 2
// 293.532 us; speedup vs baseline: 1.3240x; 1.3060x over previous
//
#include <hip/hip_runtime.h>

#define B_  4
#define N_  131072
#define J_  55
#define JP_ 56        // padded J (pad entries are zero)
#define D_  64
#define D3_ 262144    // 64^3
#define PF_ 486
#define COLS_ 31425   // M*3

#define BL16(u) __uint_as_float((u) << 16)
#define BH16(u) __uint_as_float((u) & 0xffff0000u)

// native 4-float vector for nontemporal builtins (HIP float4 is a class)
typedef float vfloat4 __attribute__((ext_vector_type(4)));

__device__ __forceinline__ unsigned short f2bf(float v) {
    unsigned u = __float_as_uint(v);
    u += 0x7fffu + ((u >> 16) & 1u);   // round-to-nearest-even
    return (unsigned short)(u >> 16);
}

// ------- off_full: pose part (pf @ podir, p-chunked) + shape part at pc==0 -
__global__ void k_off_pose(const float* __restrict__ pf,
                           const float* __restrict__ podir,
                           const float* __restrict__ betas,
                           const float* __restrict__ spdir,
                           float* __restrict__ off_full) {
    int col = blockIdx.x * 256 + threadIdx.x;
    if (col >= COLS_) return;
    int pc = blockIdx.y;
    float a0 = 0.f, a1 = 0.f, a2 = 0.f, a3 = 0.f;
    if (pc == 0) {   // shape blend term rides along in chunk 0
        float sp[10];
#pragma unroll
        for (int l = 0; l < 10; ++l) sp[l] = spdir[col * 10 + l];
#pragma unroll
        for (int l = 0; l < 10; ++l) {
            a0 += betas[0 * 10 + l] * sp[l];
            a1 += betas[1 * 10 + l] * sp[l];
            a2 += betas[2 * 10 + l] * sp[l];
            a3 += betas[3 * 10 + l] * sp[l];
        }
    }
    int p0 = pc * 61;
    int p1 = p0 + 61; if (p1 > PF_) p1 = PF_;
    int p = p0;
    for (; p + 4 <= p1; p += 4) {         // 4 loads in flight
        float v0 = podir[(size_t)(p + 0) * COLS_ + col];
        float v1 = podir[(size_t)(p + 1) * COLS_ + col];
        float v2 = podir[(size_t)(p + 2) * COLS_ + col];
        float v3 = podir[(size_t)(p + 3) * COLS_ + col];
        a0 += pf[0 * PF_ + p] * v0 + pf[0 * PF_ + p + 1] * v1 +
              pf[0 * PF_ + p + 2] * v2 + pf[0 * PF_ + p + 3] * v3;
        a1 += pf[1 * PF_ + p] * v0 + pf[1 * PF_ + p + 1] * v1 +
              pf[1 * PF_ + p + 2] * v2 + pf[1 * PF_ + p + 3] * v3;
        a2 += pf[2 * PF_ + p] * v0 + pf[2 * PF_ + p + 1] * v1 +
              pf[2 * PF_ + p + 2] * v2 + pf[2 * PF_ + p + 3] * v3;
        a3 += pf[3 * PF_ + p] * v0 + pf[3 * PF_ + p + 1] * v1 +
              pf[3 * PF_ + p + 2] * v2 + pf[3 * PF_ + p + 3] * v3;
    }
    for (; p < p1; ++p) {
        float v = podir[(size_t)p * COLS_ + col];
        a0 += pf[0 * PF_ + p] * v;
        a1 += pf[1 * PF_ + p] * v;
        a2 += pf[2 * PF_ + p] * v;
        a3 += pf[3 * PF_ + p] * v;
    }
    atomicAdd(&off_full[0 * COLS_ + col], a0);
    atomicAdd(&off_full[1 * COLS_ + col], a1);
    atomicAdd(&off_full[2 * COLS_ + col], a2);
    atomicAdd(&off_full[3 * COLS_ + col], a3);
}

// ---------------- tfs = A @ A_inv, padded to JP_ joints --------------------
__global__ void k_tfs(const float* __restrict__ A,
                      const float* __restrict__ Ainv,
                      float* __restrict__ tfsP) {
    int tid = blockIdx.x * 256 + threadIdx.x;
    if (tid >= B_ * JP_ * 16) return;
    int rc = tid & 15;
    int jb = tid >> 4;
    int j = jb % JP_;
    int b = jb / JP_;
    float v = 0.f;
    if (j < J_) {
        int r = rc >> 2, c = rc & 3;
#pragma unroll
        for (int k = 0; k < 4; ++k)
            v += A[((b * J_ + j) * 4 + r) * 4 + k] * Ainv[(j * 4 + k) * 4 + c];
    }
    tfsP[tid] = v;
}

// --- k_G: per-grid-vertex blended transform  G[b][v][16] (bf16), S[v] (f32)
// G[v] = sum_j vox[j][v] * tfs[b][j];  S[v] = sum_j vox[j][v]  (b-independent)
// Exploits linearity of trilerp: T(p) = sum_corners wc * G[corner].
__global__ __launch_bounds__(256) void k_G(
    const float* __restrict__ vox, const float* __restrict__ tfsP,
    uint4* __restrict__ Gtb, float* __restrict__ Stb) {
    int v = blockIdx.x * 256 + threadIdx.x;
    float g[4][16];
    float s = 0.f;
#pragma unroll
    for (int b = 0; b < 4; ++b)
#pragma unroll
        for (int r = 0; r < 16; ++r) g[b][r] = 0.f;
    for (int j0 = 0; j0 < J_; j0 += 5) {   // 55 = 11 x 5; 5 loads in flight
        float wv[5];
#pragma unroll
        for (int k = 0; k < 5; ++k)
            wv[k] = vox[(size_t)(j0 + k) * D3_ + v];
#pragma unroll
        for (int k = 0; k < 5; ++k) {
            float w = wv[k];
            s += w;
#pragma unroll
            for (int b = 0; b < 4; ++b) {
                const float* tr = tfsP + (b * JP_ + j0 + k) * 16;  // s_load
#pragma unroll
                for (int r = 0; r < 16; ++r) g[b][r] += w * tr[r];
            }
        }
    }
    Stb[v] = s;
#pragma unroll
    for (int b = 0; b < 4; ++b) {
        unsigned gw[8];
#pragma unroll
        for (int k = 0; k < 8; ++k)
            gw[k] = (unsigned)f2bf(g[b][2 * k]) |
                    ((unsigned)f2bf(g[b][2 * k + 1]) << 16);
        uint4* gp = Gtb + ((size_t)b * D3_ + v) * 2;
        gp[0] = make_uint4(gw[0], gw[1], gw[2], gw[3]);
        gp[1] = make_uint4(gw[4], gw[5], gw[6], gw[7]);
    }
}

// accumulate 8 T-entries from two adjacent-corner G rows (bf16-packed)
#define ACC8(Toff, qa, qb)                                 \
    T[Toff + 0] += w0 * BL16(qa.x) + w1 * BL16(qb.x);      \
    T[Toff + 1] += w0 * BH16(qa.x) + w1 * BH16(qb.x);      \
    T[Toff + 2] += w0 * BL16(qa.y) + w1 * BL16(qb.y);      \
    T[Toff + 3] += w0 * BH16(qa.y) + w1 * BH16(qb.y);      \
    T[Toff + 4] += w0 * BL16(qa.z) + w1 * BL16(qb.z);      \
    T[Toff + 5] += w0 * BH16(qa.z) + w1 * BH16(qb.z);      \
    T[Toff + 6] += w0 * BL16(qa.w) + w1 * BL16(qb.w);      \
    T[Toff + 7] += w0 * BH16(qa.w) + w1 * BH16(qb.w);

// ------- single fused main pass with intra-block mask compaction -----------
// Phase A: all 256 threads compute canonical x (+ voxel cell/fracs) and stage
// in LDS; ballot/prefix builds a permutation with voxel points first.
// Phase B: thread t processes point lst[t] -> each wave runs ONE path.
__global__ __launch_bounds__(256) void k_main(
    const float* __restrict__ pts, const int* __restrict__ faces,
    const float* __restrict__ poseoff, const int* __restrict__ mask,
    const float* __restrict__ vox_scale, const float* __restrict__ vox_offset,
    const float* __restrict__ off_full, const float* __restrict__ tfsP,
    const float* __restrict__ lbsw, const uint4* __restrict__ Gtb,
    const float* __restrict__ Stb,
    float* __restrict__ out_posed, float* __restrict__ out_T) {
    __shared__ float sx0[256], sx1[256], sx2[256];
    __shared__ float sf0[256], sf1[256], sf2[256];
    __shared__ int   scell[256];
    __shared__ unsigned short lst[256];
    __shared__ int wc[4];

    // XCD-aware decode: grid.x = 2048; xcd = bid%8 (round-robin dispatch),
    // b = (bid>>1)&3 -> each XCD pair works one batch's G-plane (L2 locality)
    int bid = blockIdx.x;
    int b  = (bid >> 1) & 3;
    int nc = ((bid >> 3) << 1) | (bid & 1);     // [0,512) per b, bijective
    int tid = threadIdx.x;
    int n = nc * 256 + tid;
    int i = (b << 17) | n;

    float px = pts[3 * i + 0], py = pts[3 * i + 1], pz = pts[3 * i + 2];
    int f0 = faces[3 * n + 0], f1 = faces[3 * n + 1], f2 = faces[3 * n + 2];
    const float* ob = off_full + b * COLS_;
    const float c3 = 1.f / 3.f;
    float ox = (ob[f0 * 3 + 0] + ob[f1 * 3 + 0] + ob[f2 * 3 + 0]) * c3;
    float oy = (ob[f0 * 3 + 1] + ob[f1 * 3 + 1] + ob[f2 * 3 + 1]) * c3;
    float oz = (ob[f0 * 3 + 2] + ob[f1 * 3 + 2] + ob[f2 * 3 + 2]) * c3;
    sx0[tid] = px + ox - poseoff[3 * n + 0];
    sx1[tid] = py + oy - poseoff[3 * n + 1];
    sx2[tid] = pz + oz - poseoff[3 * n + 2];

    bool isv = !(mask[i] > 0);
    if (isv) {
        float sxc = vox_scale[0], syc = vox_scale[1], szc = vox_scale[2];
        float o0 = vox_offset[0], o1 = vox_offset[1], o2 = vox_offset[2];
        float gx = fminf(fmaxf(px * sxc + o0, -1.f), 1.f);
        float gy = fminf(fmaxf(py * syc + o1, -1.f), 1.f);
        float gz = fminf(fmaxf(pz * szc + o2, -1.f), 1.f);
        float tx = (gx + 1.f) * 0.5f * (D_ - 1);
        float ty = (gy + 1.f) * 0.5f * (D_ - 1);
        float tz = (gz + 1.f) * 0.5f * (D_ - 1);
        int ix = (int)floorf(tx); if (ix > D_ - 2) ix = D_ - 2; if (ix < 0) ix = 0;
        int iy = (int)floorf(ty); if (iy > D_ - 2) iy = D_ - 2; if (iy < 0) iy = 0;
        int iz = (int)floorf(tz); if (iz > D_ - 2) iz = D_ - 2; if (iz < 0) iz = 0;
        sf0[tid] = tx - ix;
        sf1[tid] = ty - iy;
        sf2[tid] = tz - iz;
        scell[tid] = (ix * D_ + iy) * D_ + iz;
    }

    unsigned long long bal = __ballot(isv);
    int lane = tid & 63, wid = tid >> 6;
    if (lane == 0) wc[wid] = __popcll(bal);
    __syncthreads();
    int pre = 0;
#pragma unroll
    for (int k = 0; k < 4; ++k) pre += (k < wid) ? wc[k] : 0;
    int tot = wc[0] + wc[1] + wc[2] + wc[3];
    unsigned long long lt = ((unsigned long long)1 << lane) - 1ull;
    int vbefore = pre + __popcll(bal & lt);       // voxel threads before me
    int pos = isv ? vbefore : (tot + (tid - vbefore));
    lst[pos] = (unsigned short)tid;
    __syncthreads();

    int slot = lst[tid];
    float x0 = sx0[slot], x1 = sx1[slot], x2 = sx2[slot];
    int ii = (b << 17) | (nc * 256 + slot);

    float T[16];
#pragma unroll
    for (int r = 0; r < 16; ++r) T[r] = 0.f;
    float wsum = 0.f;

    if (tid < tot) {
        // voxel path: 8-corner blend of precomputed per-vertex transforms
        float fx = sf0[slot], fy = sf1[slot], fz = sf2[slot];
        int cell = scell[slot];
        const uint4* Gb = Gtb + (size_t)b * D3_ * 2;
#pragma unroll
        for (int cc = 0; cc < 4; ++cc) {
            int fid = cell + ((cc & 2) ? D_ * D_ : 0) + ((cc & 1) ? D_ : 0);
            float wxy = ((cc & 2) ? fx : 1.f - fx) * ((cc & 1) ? fy : 1.f - fy);
            float w0 = wxy * (1.f - fz);
            float w1 = wxy * fz;
            const uint4* R = Gb + (size_t)fid * 2;   // 64B: rows fid, fid+1
            uint4 q0 = R[0], q1 = R[1], q2 = R[2], q3 = R[3];
            wsum += w0 * Stb[fid] + w1 * Stb[fid + 1];
            ACC8(0, q0, q2)
            ACC8(8, q1, q3)
        }
    } else {
        // explicit skinning weights path, 8 loads in flight per chunk
        int n2 = nc * 256 + slot;
        const float* lw = lbsw + (size_t)n2 * J_;
        const float* tb = tfsP + b * (JP_ * 16);   // uniform -> s_load
        float wv[8];
        for (int c = 0; c < 6; ++c) {              // 48 of 55
#pragma unroll
            for (int k = 0; k < 8; ++k) wv[k] = lw[c * 8 + k];
#pragma unroll
            for (int k = 0; k < 8; ++k) {
                float w = wv[k];
                wsum += w;
                const float* tr = tb + (c * 8 + k) * 16;
#pragma unroll
                for (int r = 0; r < 16; ++r) T[r] += w * tr[r];
            }
        }
#pragma unroll
        for (int k = 0; k < 7; ++k) wv[k] = lw[48 + k];   // tail 7
#pragma unroll
        for (int k = 0; k < 7; ++k) {
            float w = wv[k];
            wsum += w;
            const float* tr = tb + (48 + k) * 16;
#pragma unroll
            for (int r = 0; r < 16; ++r) T[r] += w * tr[r];
        }
    }

    float inv = 1.f / fmaxf(wsum, 1e-8f);
    float t[16];
#pragma unroll
    for (int r = 0; r < 16; ++r) t[r] = T[r] * inv;
    out_posed[3 * ii + 0] = t[0] * x0 + t[1] * x1 + t[2] * x2 + t[3];
    out_posed[3 * ii + 1] = t[4] * x0 + t[5] * x1 + t[6] * x2 + t[7];
    out_posed[3 * ii + 2] = t[8] * x0 + t[9] * x1 + t[10] * x2 + t[11];
    vfloat4* to = (vfloat4*)(out_T + (size_t)ii * 16);
    vfloat4 r0 = { t[0], t[1], t[2], t[3] };
    vfloat4 r1 = { t[4], t[5], t[6], t[7] };
    vfloat4 r2 = { t[8], t[9], t[10], t[11] };
    vfloat4 r3 = { t[12], t[13], t[14], t[15] };
    __builtin_nontemporal_store(r0, to + 0);
    __builtin_nontemporal_store(r1, to + 1);
    __builtin_nontemporal_store(r2, to + 2);
    __builtin_nontemporal_store(r3, to + 3);
}

extern "C" void kernel_launch(void* const* d_in, const int* in_sizes, int n_in,
                              void* d_out, int out_size, void* d_ws, size_t ws_size,
                              hipStream_t stream) {
    const float* pts      = (const float*)d_in[0];
    const float* betas    = (const float*)d_in[1];
    const float* pf       = (const float*)d_in[2];
    const float* spdir    = (const float*)d_in[3];
    const float* podir    = (const float*)d_in[4];
    const int*   faces    = (const int*)d_in[5];
    const float* tfs_A    = (const float*)d_in[6];
    const float* tfs_inv  = (const float*)d_in[7];
    const float* poseoff  = (const float*)d_in[8];
    const float* lbsw     = (const float*)d_in[9];
    const float* vox      = (const float*)d_in[10];
    const float* vscale   = (const float*)d_in[11];
    const float* voffset  = (const float*)d_in[12];
    const int*   mask     = (const int*)d_in[13];

    // workspace layout (256B-aligned)
    char* w = (char*)d_ws;
    uint4* Gtb      = (uint4*)w;                       // 33,554,432 B
    float* Stb      = (float*)(w + 33554432);          //  1,048,576 B
    float* off_full = (float*)(w + 34603008);          //    503,040 B
    float* tfsP     = (float*)(w + 35106048);          //     14,336 B
    // total: 35,120,384 B

    float* out_posed = (float*)d_out;
    float* out_T     = out_posed + (size_t)B_ * N_ * 3;

    (void)hipMemsetAsync(off_full, 0, 503040, stream);
    k_tfs<<<(B_ * JP_ * 16 + 255) / 256, 256, 0, stream>>>(tfs_A, tfs_inv, tfsP);
    k_G<<<D3_ / 256, 256, 0, stream>>>(vox, tfsP, Gtb, Stb);
    dim3 gpose((COLS_ + 255) / 256, 8);
    k_off_pose<<<gpose, 256, 0, stream>>>(pf, podir, betas, spdir, off_full);

    k_main<<<2048, 256, 0, stream>>>(pts, faces, poseoff, mask, vscale, voffset,
                                     off_full, tfsP, lbsw, Gtb, Stb,
                                     out_posed, out_T);
}

// Round 3
// 292.673 us; speedup vs baseline: 1.3278x; 1.0029x over previous
//
#include <hip/hip_runtime.h>

#define B_  4
#define N_  131072
#define J_  55
#define JP_ 56        // padded J (pad entries are zero)
#define D_  64
#define D3_ 262144    // 64^3
#define PF_ 486
#define COLS_ 31425   // M*3

// prelude zone sizes (blocks)
#define GZ_ 1024      // G-blend zone: D3_/256
#define OZ_ 1968      // off_pose zone: 123 col-blocks x 16 p-chunks
#define PZ_ 14336     // lbsw pack zone: N_*28/256

#define BL16(u) __uint_as_float((u) << 16)
#define BH16(u) __uint_as_float((u) & 0xffff0000u)

typedef float vfloat4 __attribute__((ext_vector_type(4)));

__device__ __forceinline__ unsigned short f2bf(float v) {
    unsigned u = __float_as_uint(v);
    u += 0x7fffu + ((u >> 16) & 1u);   // round-to-nearest-even
    return (unsigned short)(u >> 16);
}

// ------ k_tfs_zero: tfs = A @ A_inv (padded) + zero off_full, one launch ---
__global__ __launch_bounds__(256) void k_tfs_zero(
    const float* __restrict__ A, const float* __restrict__ Ainv,
    float* __restrict__ tfsP, float4* __restrict__ off_zero) {
    int bx = blockIdx.x;
    if (bx < 14) {                       // 14*256 == B_*JP_*16 == 3584
        int tid = bx * 256 + threadIdx.x;
        int rc = tid & 15;
        int jb = tid >> 4;
        int j = jb % JP_;
        int b = jb / JP_;
        float v = 0.f;
        if (j < J_) {
            int r = rc >> 2, c = rc & 3;
#pragma unroll
            for (int k = 0; k < 4; ++k)
                v += A[((b * J_ + j) * 4 + r) * 4 + k] *
                     Ainv[(j * 4 + k) * 4 + c];
        }
        tfsP[tid] = v;
    } else {                             // blocks 14..136: zero 503808 B
        int idx = (bx - 14) * 256 + threadIdx.x;   // 123*256 float4s
        off_zero[idx] = make_float4(0.f, 0.f, 0.f, 0.f);
    }
}

// ------ k_prelude: three independent zones overlap on the GPU --------------
// zone G  [0, GZ_):        G[b][v][16] bf16 + S[v] f32 (trilerp linearity)
// zone O  [GZ_, GZ_+OZ_):  off_full = betas@spdir + pf@podir (atomic combine)
// zone P  [GZ_+OZ_, ...):  pack lbsw f32[N][55] -> bf16[N][56] (112B rows)
__global__ __launch_bounds__(256) void k_prelude(
    const float* __restrict__ vox, const float* __restrict__ tfsP,
    uint4* __restrict__ Gtb, float* __restrict__ Stb,
    const float* __restrict__ pf, const float* __restrict__ podir,
    const float* __restrict__ betas, const float* __restrict__ spdir,
    float* __restrict__ off_full,
    const float* __restrict__ lbsw, unsigned* __restrict__ lbswP32) {
    int bx = blockIdx.x;
    int tid = threadIdx.x;

    if (bx < GZ_) {
        // ---- G zone: 1-group-ahead pipelined j-loop (loads hide under FMA)
        int v = bx * 256 + tid;
        float g[4][16];
        float s = 0.f;
#pragma unroll
        for (int b = 0; b < 4; ++b)
#pragma unroll
            for (int r = 0; r < 16; ++r) g[b][r] = 0.f;
        float wa[5], wb[5];
#pragma unroll
        for (int k = 0; k < 5; ++k) wa[k] = vox[(size_t)k * D3_ + v];
        for (int j0 = 0; j0 < J_; j0 += 5) {
            if (j0 + 5 < J_) {
#pragma unroll
                for (int k = 0; k < 5; ++k)
                    wb[k] = vox[(size_t)(j0 + 5 + k) * D3_ + v];
            }
#pragma unroll
            for (int k = 0; k < 5; ++k) {
                float w = wa[k];
                s += w;
#pragma unroll
                for (int b = 0; b < 4; ++b) {
                    const float* tr = tfsP + (b * JP_ + j0 + k) * 16; // s_load
#pragma unroll
                    for (int r = 0; r < 16; ++r) g[b][r] += w * tr[r];
                }
            }
#pragma unroll
            for (int k = 0; k < 5; ++k) wa[k] = wb[k];
        }
        Stb[v] = s;
#pragma unroll
        for (int b = 0; b < 4; ++b) {
            unsigned gw[8];
#pragma unroll
            for (int k = 0; k < 8; ++k)
                gw[k] = (unsigned)f2bf(g[b][2 * k]) |
                        ((unsigned)f2bf(g[b][2 * k + 1]) << 16);
            uint4* gp = Gtb + ((size_t)b * D3_ + v) * 2;
            gp[0] = make_uint4(gw[0], gw[1], gw[2], gw[3]);
            gp[1] = make_uint4(gw[4], gw[5], gw[6], gw[7]);
        }
    } else if (bx < GZ_ + OZ_) {
        // ---- off_pose zone: 16 p-chunks of ~31, 8 loads in flight
        int idx = bx - GZ_;
        int colb = idx % 123;
        int pc = idx / 123;
        int col = colb * 256 + tid;
        if (col >= COLS_) return;
        float a0 = 0.f, a1 = 0.f, a2 = 0.f, a3 = 0.f;
        if (pc == 0) {   // shape blend term rides along in chunk 0
            float sp[10];
#pragma unroll
            for (int l = 0; l < 10; ++l) sp[l] = spdir[col * 10 + l];
#pragma unroll
            for (int l = 0; l < 10; ++l) {
                a0 += betas[0 * 10 + l] * sp[l];
                a1 += betas[1 * 10 + l] * sp[l];
                a2 += betas[2 * 10 + l] * sp[l];
                a3 += betas[3 * 10 + l] * sp[l];
            }
        }
        int p0 = pc * 31;
        int p1 = p0 + 31; if (p1 > PF_) p1 = PF_;
        int p = p0;
        for (; p + 8 <= p1; p += 8) {
            float v8[8];
#pragma unroll
            for (int k = 0; k < 8; ++k)
                v8[k] = podir[(size_t)(p + k) * COLS_ + col];
#pragma unroll
            for (int k = 0; k < 8; ++k) {
                a0 += pf[0 * PF_ + p + k] * v8[k];
                a1 += pf[1 * PF_ + p + k] * v8[k];
                a2 += pf[2 * PF_ + p + k] * v8[k];
                a3 += pf[3 * PF_ + p + k] * v8[k];
            }
        }
        for (; p < p1; ++p) {
            float v = podir[(size_t)p * COLS_ + col];
            a0 += pf[0 * PF_ + p] * v;
            a1 += pf[1 * PF_ + p] * v;
            a2 += pf[2 * PF_ + p] * v;
            a3 += pf[3 * PF_ + p] * v;
        }
        atomicAdd(&off_full[0 * COLS_ + col], a0);
        atomicAdd(&off_full[1 * COLS_ + col], a1);
        atomicAdd(&off_full[2 * COLS_ + col], a2);
        atomicAdd(&off_full[3 * COLS_ + col], a3);
    } else {
        // ---- pack zone: element e -> row n = e/28, word jj = e%28
        int e = (bx - GZ_ - OZ_) * 256 + tid;     // PZ_*256 == N_*28 exactly
        int n = e / 28;
        int jj = e - n * 28;
        int j0 = 2 * jj;
        float w0 = lbsw[(size_t)n * J_ + j0];
        float w1 = (j0 + 1 < J_) ? lbsw[(size_t)n * J_ + j0 + 1] : 0.f;
        lbswP32[e] = (unsigned)f2bf(w0) | ((unsigned)f2bf(w1) << 16);
    }
}

// accumulate 8 T-entries from two adjacent-corner G rows (bf16-packed)
#define ACC8(Toff, qa, qb)                                 \
    T[Toff + 0] += w0 * BL16(qa.x) + w1 * BL16(qb.x);      \
    T[Toff + 1] += w0 * BH16(qa.x) + w1 * BH16(qb.x);      \
    T[Toff + 2] += w0 * BL16(qa.y) + w1 * BL16(qb.y);      \
    T[Toff + 3] += w0 * BH16(qa.y) + w1 * BH16(qb.y);      \
    T[Toff + 4] += w0 * BL16(qa.z) + w1 * BL16(qb.z);      \
    T[Toff + 5] += w0 * BH16(qa.z) + w1 * BH16(qb.z);      \
    T[Toff + 6] += w0 * BL16(qa.w) + w1 * BL16(qb.w);      \
    T[Toff + 7] += w0 * BH16(qa.w) + w1 * BH16(qb.w);

// ------- fused main pass: compaction + LDS-restored coalesced stores -------
__global__ __launch_bounds__(256) void k_main(
    const float* __restrict__ pts, const int* __restrict__ faces,
    const float* __restrict__ poseoff, const int* __restrict__ mask,
    const float* __restrict__ vox_scale, const float* __restrict__ vox_offset,
    const float* __restrict__ off_full, const float* __restrict__ tfsP,
    const unsigned short* __restrict__ lbswP, const uint4* __restrict__ Gtb,
    const float* __restrict__ Stb,
    float* __restrict__ out_posed, float* __restrict__ out_T) {
    __shared__ float sx0[256], sx1[256], sx2[256];
    __shared__ float sf0[256], sf1[256], sf2[256];
    __shared__ int   scell[256];
    __shared__ float sT[256 * 16];
    __shared__ unsigned short lst[256];
    __shared__ int wc[4];

    // XCD binding: round-robin dispatch puts bid%8 on XCD (bid%8).
    // b = (bid&7)>>1 -> XCD pair {2b,2b+1} only ever touches batch b's
    // G-plane (8.4MB) -> L2 locality. nc = ((bid>>3)<<1)|(bid&1) bijective.
    int bid = blockIdx.x;
    int b  = (bid & 7) >> 1;
    int nc = ((bid >> 3) << 1) | (bid & 1);     // [0,512) per b
    int tid = threadIdx.x;
    int n = nc * 256 + tid;
    int i = (b << 17) | n;

    float px = pts[3 * i + 0], py = pts[3 * i + 1], pz = pts[3 * i + 2];
    int f0 = faces[3 * n + 0], f1 = faces[3 * n + 1], f2 = faces[3 * n + 2];
    const float* ob = off_full + b * COLS_;
    const float c3 = 1.f / 3.f;
    float ox = (ob[f0 * 3 + 0] + ob[f1 * 3 + 0] + ob[f2 * 3 + 0]) * c3;
    float oy = (ob[f0 * 3 + 1] + ob[f1 * 3 + 1] + ob[f2 * 3 + 1]) * c3;
    float oz = (ob[f0 * 3 + 2] + ob[f1 * 3 + 2] + ob[f2 * 3 + 2]) * c3;
    sx0[tid] = px + ox - poseoff[3 * n + 0];
    sx1[tid] = py + oy - poseoff[3 * n + 1];
    sx2[tid] = pz + oz - poseoff[3 * n + 2];

    bool isv = !(mask[i] > 0);
    if (isv) {
        float sxc = vox_scale[0], syc = vox_scale[1], szc = vox_scale[2];
        float o0 = vox_offset[0], o1 = vox_offset[1], o2 = vox_offset[2];
        float gx = fminf(fmaxf(px * sxc + o0, -1.f), 1.f);
        float gy = fminf(fmaxf(py * syc + o1, -1.f), 1.f);
        float gz = fminf(fmaxf(pz * szc + o2, -1.f), 1.f);
        float tx = (gx + 1.f) * 0.5f * (D_ - 1);
        float ty = (gy + 1.f) * 0.5f * (D_ - 1);
        float tz = (gz + 1.f) * 0.5f * (D_ - 1);
        int ix = (int)floorf(tx); if (ix > D_ - 2) ix = D_ - 2; if (ix < 0) ix = 0;
        int iy = (int)floorf(ty); if (iy > D_ - 2) iy = D_ - 2; if (iy < 0) iy = 0;
        int iz = (int)floorf(tz); if (iz > D_ - 2) iz = D_ - 2; if (iz < 0) iz = 0;
        sf0[tid] = tx - ix;
        sf1[tid] = ty - iy;
        sf2[tid] = tz - iz;
        scell[tid] = (ix * D_ + iy) * D_ + iz;
    }

    unsigned long long bal = __ballot(isv);
    int lane = tid & 63, wid = tid >> 6;
    if (lane == 0) wc[wid] = __popcll(bal);
    __syncthreads();
    int pre = 0;
#pragma unroll
    for (int k = 0; k < 4; ++k) pre += (k < wid) ? wc[k] : 0;
    int tot = wc[0] + wc[1] + wc[2] + wc[3];
    unsigned long long lt = ((unsigned long long)1 << lane) - 1ull;
    int vbefore = pre + __popcll(bal & lt);       // voxel threads before me
    int pos = isv ? vbefore : (tot + (tid - vbefore));
    lst[pos] = (unsigned short)tid;
    __syncthreads();

    int slot = lst[tid];
    float x0 = sx0[slot], x1 = sx1[slot], x2 = sx2[slot];

    float T[16];
#pragma unroll
    for (int r = 0; r < 16; ++r) T[r] = 0.f;
    float wsum = 0.f;

    if (tid < tot) {
        // voxel path: 8-corner blend of precomputed per-vertex transforms
        float fx = sf0[slot], fy = sf1[slot], fz = sf2[slot];
        int cell = scell[slot];
        const uint4* Gb = Gtb + (size_t)b * D3_ * 2;
#pragma unroll
        for (int cc = 0; cc < 4; ++cc) {
            int fid = cell + ((cc & 2) ? D_ * D_ : 0) + ((cc & 1) ? D_ : 0);
            float wxy = ((cc & 2) ? fx : 1.f - fx) * ((cc & 1) ? fy : 1.f - fy);
            float w0 = wxy * (1.f - fz);
            float w1 = wxy * fz;
            const uint4* R = Gb + (size_t)fid * 2;   // 64B: rows fid, fid+1
            uint4 q0 = R[0], q1 = R[1], q2 = R[2], q3 = R[3];
            wsum += w0 * Stb[fid] + w1 * Stb[fid + 1];
            ACC8(0, q0, q2)
            ACC8(8, q1, q3)
        }
    } else {
        // lbsw path: 7 aligned uint4 of packed bf16 weights, 1 vmcnt wait
        int n2 = nc * 256 + slot;
        const uint4* lw = (const uint4*)(lbswP + (size_t)n2 * 56);
        uint4 q[7];
#pragma unroll
        for (int k = 0; k < 7; ++k) q[k] = lw[k];
        const float* tb = tfsP + b * (JP_ * 16);   // uniform -> s_load
#pragma unroll
        for (int k = 0; k < 7; ++k) {
            float w8[8];
            w8[0] = BL16(q[k].x); w8[1] = BH16(q[k].x);
            w8[2] = BL16(q[k].y); w8[3] = BH16(q[k].y);
            w8[4] = BL16(q[k].z); w8[5] = BH16(q[k].z);
            w8[6] = BL16(q[k].w); w8[7] = BH16(q[k].w);
#pragma unroll
            for (int m = 0; m < 8; ++m) {
                float w = w8[m];          // j = 8k+m; j==55 slot is 0 pad
                wsum += w;
                const float* tr = tb + (k * 8 + m) * 16;
#pragma unroll
                for (int r = 0; r < 16; ++r) T[r] += w * tr[r];
            }
        }
    }

    float inv = 1.f / fmaxf(wsum, 1e-8f);
    float t[16];
#pragma unroll
    for (int r = 0; r < 16; ++r) t[r] = T[r] * inv;
    // stage results at slot; each LDS location touched only by its owner
    sx0[slot] = t[0] * x0 + t[1] * x1 + t[2] * x2 + t[3];
    sx1[slot] = t[4] * x0 + t[5] * x1 + t[6] * x2 + t[7];
    sx2[slot] = t[8] * x0 + t[9] * x1 + t[10] * x2 + t[11];
#pragma unroll
    for (int r = 0; r < 16; ++r) sT[slot * 16 + r] = t[r];
    __syncthreads();

    // coalesced stores in original tid order
    out_posed[3 * i + 0] = sx0[tid];
    out_posed[3 * i + 1] = sx1[tid];
    out_posed[3 * i + 2] = sx2[tid];
    vfloat4* to = (vfloat4*)(out_T + (size_t)i * 16);
#pragma unroll
    for (int k = 0; k < 4; ++k) {
        vfloat4 r = { sT[tid * 16 + 4 * k + 0], sT[tid * 16 + 4 * k + 1],
                      sT[tid * 16 + 4 * k + 2], sT[tid * 16 + 4 * k + 3] };
        __builtin_nontemporal_store(r, to + k);
    }
}

extern "C" void kernel_launch(void* const* d_in, const int* in_sizes, int n_in,
                              void* d_out, int out_size, void* d_ws, size_t ws_size,
                              hipStream_t stream) {
    const float* pts      = (const float*)d_in[0];
    const float* betas    = (const float*)d_in[1];
    const float* pf       = (const float*)d_in[2];
    const float* spdir    = (const float*)d_in[3];
    const float* podir    = (const float*)d_in[4];
    const int*   faces    = (const int*)d_in[5];
    const float* tfs_A    = (const float*)d_in[6];
    const float* tfs_inv  = (const float*)d_in[7];
    const float* poseoff  = (const float*)d_in[8];
    const float* lbsw     = (const float*)d_in[9];
    const float* vox      = (const float*)d_in[10];
    const float* vscale   = (const float*)d_in[11];
    const float* voffset  = (const float*)d_in[12];
    const int*   mask     = (const int*)d_in[13];

    // workspace layout (256B-aligned)
    char* w = (char*)d_ws;
    uint4* Gtb              = (uint4*)w;                   // 33,554,432 B
    float* Stb              = (float*)(w + 33554432);      //  1,048,576 B
    unsigned short* lbswP   = (unsigned short*)(w + 34603008); // 14,680,064 B
    float* off_full         = (float*)(w + 49283072);      //    516,096 B (padded)
    float* tfsP             = (float*)(w + 49799168);      //     14,336 B
    // total: 49,813,504 B

    float* out_posed = (float*)d_out;
    float* out_T     = out_posed + (size_t)B_ * N_ * 3;

    k_tfs_zero<<<137, 256, 0, stream>>>(tfs_A, tfs_inv, tfsP,
                                        (float4*)off_full);
    k_prelude<<<GZ_ + OZ_ + PZ_, 256, 0, stream>>>(
        vox, tfsP, Gtb, Stb, pf, podir, betas, spdir, off_full,
        lbsw, (unsigned*)lbswP);
    k_main<<<2048, 256, 0, stream>>>(pts, faces, poseoff, mask, vscale,
                                     voffset, off_full, tfsP, lbswP, Gtb, Stb,
                                     out_posed, out_T);
}